// Round 6
// baseline (230.566 us; speedup 1.0000x reference)
//
#include <hip/hip_runtime.h>
#include <cstddef>

constexpr int NN  = 40000;   // nodes
constexpr int NE  = 640000;  // edges
constexpr int DIM = 128;     // D_IN == D_OUT
constexpr int CAP = 48;      // per-node neighbor capacity (max deg ~36 for Poisson(16))
constexpr int PLANE = NN * 64;  // shorts per 64-dim plane

typedef __attribute__((ext_vector_type(8))) short short8;   // 8 bf16 (4 VGPRs)
typedef __attribute__((ext_vector_type(4))) float floatx4;  // MFMA acc

// fp32 -> bf16 with round-to-nearest-even
__device__ __forceinline__ unsigned short f2bf(float x) {
    union { float f; unsigned int i; } v; v.f = x;
    unsigned int u = v.i;
    return (unsigned short)((u + 0x7fffu + ((u >> 16) & 1u)) >> 16);
}
__device__ __forceinline__ float bflo2f(unsigned int u) {   // low bf16 -> f32
    union { unsigned int i; float f; } v; v.i = u << 16; return v.f;
}
__device__ __forceinline__ float bfhi2f(unsigned int u) {   // high bf16 -> f32
    union { unsigned int i; float f; } v; v.i = u & 0xffff0000u; return v.f;
}

// ---------------------------------------------------------------------------
// Prep: [blocks 0..2499] cast feat fp32 -> bf16 planes featb[2][NN][64]
//       [blocks 2500..2627] transpose+cast W to Wc[4][128][64]
//       [blocks 2628..2784] zero cnt[NN]
// ---------------------------------------------------------------------------
__global__ __launch_bounds__(256) void k_prep(
    const float* __restrict__ feat, const float* __restrict__ Wself,
    const float* __restrict__ Wneigh, unsigned short* __restrict__ featb,
    unsigned short* __restrict__ Wc, int* __restrict__ cnt)
{
    int b = blockIdx.x, t = threadIdx.x;
    if (b < 2500) {
        int idx8 = b * 256 + t;          // 640000 groups of 8 elements
        int n  = idx8 >> 4;              // 16 groups per row
        int d0 = (idx8 & 15) << 3;       // dim base 0,8,...,120
        const float4* fp =
            reinterpret_cast<const float4*>(feat + (size_t)n * DIM + d0);
        float4 v0 = fp[0], v1 = fp[1];
        unsigned int p0 = (unsigned int)f2bf(v0.x) | ((unsigned int)f2bf(v0.y) << 16);
        unsigned int p1 = (unsigned int)f2bf(v0.z) | ((unsigned int)f2bf(v0.w) << 16);
        unsigned int p2 = (unsigned int)f2bf(v1.x) | ((unsigned int)f2bf(v1.y) << 16);
        unsigned int p3 = (unsigned int)f2bf(v1.z) | ((unsigned int)f2bf(v1.w) << 16);
        int plane = d0 >> 6, off = d0 & 63;
        *reinterpret_cast<uint4*>(
            featb + (size_t)plane * PLANE + (size_t)n * 64 + off) =
            make_uint4(p0, p1, p2, p3);
    } else if (b < 2628) {
        int idx = (b - 2500) * 256 + t;  // 0..32767
        int c = idx >> 13, n = (idx >> 6) & 127, kp = idx & 63;
        int k = c * 64 + kp;
        float w = (k < DIM) ? Wself[(size_t)k * DIM + n]
                            : Wneigh[(size_t)(k - DIM) * DIM + n];
        Wc[idx] = f2bf(w);
    } else {
        int i = (b - 2628) * 256 + t;
        if (i < NN) cnt[i] = 0;
    }
}

// ---------------------------------------------------------------------------
// cnt re-zero (for the duplicated fill instances — instrumentation)
// ---------------------------------------------------------------------------
__global__ __launch_bounds__(256) void k_zero(int* __restrict__ cnt)
{
    int i = blockIdx.x * 256 + threadIdx.x;
    if (i < NN) cnt[i] = 0;
}

// ---------------------------------------------------------------------------
// Adjacency fill (r0 proven form).
// ---------------------------------------------------------------------------
__global__ __launch_bounds__(256) void k_fill(
    const int* __restrict__ src, const int* __restrict__ dst,
    int* __restrict__ cnt, unsigned short* __restrict__ colf)
{
    int e = blockIdx.x * blockDim.x + threadIdx.x;
    if (e < NE) {
        int d = dst[e];
        int pos = atomicAdd(&cnt[d], 1);
        if (pos < CAP) colf[d * CAP + pos] = (unsigned short)src[e];
    }
}

// ---------------------------------------------------------------------------
// Gather + mean over bf16 planes (r2/r4 proven form; idempotent — launched
// twice for instrumentation).
// ---------------------------------------------------------------------------
__global__ __launch_bounds__(256) void k_gather(
    const unsigned int* __restrict__ fb32,   // featb viewed as [2][NN][32] uint
    const int* __restrict__ cnt,
    const unsigned short* __restrict__ colf,
    unsigned int* __restrict__ hnb32)        // hnb viewed as [2][NN][32] uint
{
    int gtid = blockIdx.x * blockDim.x + threadIdx.x;
    int n = gtid >> 6;
    if (n >= NN) return;
    int lane = threadIdx.x & 63;

    int deg = cnt[n];
    int m = min(deg, CAP);
    int sv = (lane < m) ? (int)colf[n * CAP + lane] : 0;

    int vb = (lane >> 5) * (NN * 32) + (lane & 31);   // plane base + lane offset
    float ax0 = 0.f, ay0 = 0.f, ax1 = 0.f, ay1 = 0.f;
    int i = 0;
    for (; i + 7 < m; i += 8) {
        int s0 = __shfl(sv, i),     s1 = __shfl(sv, i + 1);
        int s2 = __shfl(sv, i + 2), s3 = __shfl(sv, i + 3);
        int s4 = __shfl(sv, i + 4), s5 = __shfl(sv, i + 5);
        int s6 = __shfl(sv, i + 6), s7 = __shfl(sv, i + 7);
        unsigned int u0 = fb32[vb + s0 * 32];
        unsigned int u1 = fb32[vb + s1 * 32];
        unsigned int u2 = fb32[vb + s2 * 32];
        unsigned int u3 = fb32[vb + s3 * 32];
        unsigned int u4 = fb32[vb + s4 * 32];
        unsigned int u5 = fb32[vb + s5 * 32];
        unsigned int u6 = fb32[vb + s6 * 32];
        unsigned int u7 = fb32[vb + s7 * 32];
        ax0 += bflo2f(u0); ay0 += bfhi2f(u0);
        ax1 += bflo2f(u1); ay1 += bfhi2f(u1);
        ax0 += bflo2f(u2); ay0 += bfhi2f(u2);
        ax1 += bflo2f(u3); ay1 += bfhi2f(u3);
        ax0 += bflo2f(u4); ay0 += bfhi2f(u4);
        ax1 += bflo2f(u5); ay1 += bfhi2f(u5);
        ax0 += bflo2f(u6); ay0 += bfhi2f(u6);
        ax1 += bflo2f(u7); ay1 += bfhi2f(u7);
    }
    for (; i + 3 < m; i += 4) {
        int s0 = __shfl(sv, i),     s1 = __shfl(sv, i + 1);
        int s2 = __shfl(sv, i + 2), s3 = __shfl(sv, i + 3);
        unsigned int u0 = fb32[vb + s0 * 32];
        unsigned int u1 = fb32[vb + s1 * 32];
        unsigned int u2 = fb32[vb + s2 * 32];
        unsigned int u3 = fb32[vb + s3 * 32];
        ax0 += bflo2f(u0); ay0 += bfhi2f(u0);
        ax1 += bflo2f(u1); ay1 += bfhi2f(u1);
        ax0 += bflo2f(u2); ay0 += bfhi2f(u2);
        ax1 += bflo2f(u3); ay1 += bfhi2f(u3);
    }
    for (; i < m; ++i) {
        int s0 = __shfl(sv, i);
        unsigned int u0 = fb32[vb + s0 * 32];
        ax0 += bflo2f(u0); ay0 += bfhi2f(u0);
    }
    float inv = 1.0f / fmaxf((float)deg, 1.0f);
    float ax = (ax0 + ax1) * inv, ay = (ay0 + ay1) * inv;
    hnb32[vb + n * 32] = (unsigned int)f2bf(ax) | ((unsigned int)f2bf(ay) << 16);
}

// ---------------------------------------------------------------------------
// Fused GEMM (r4 proven form, source-swizzled LDS staging).
// ---------------------------------------------------------------------------
__global__ __launch_bounds__(320) void k_gemm(
    const unsigned short* __restrict__ featb,  // [2][NN][64]
    const unsigned short* __restrict__ hnb,    // [2][NN][64]
    const unsigned short* __restrict__ Wc,     // [4][128][64]
    const float* __restrict__ bself, const float* __restrict__ bneigh,
    float* __restrict__ out)                   // [NN,128] fp32
{
    __shared__ unsigned short As[160 * 64];  // 20480 B
    __shared__ unsigned short Bs[128 * 64];  // 16384 B

    int t = threadIdx.x;
    int w = t >> 6;
    int lane = t & 63;
    int base_m = blockIdx.x * 160;

    floatx4 acc[2][8];
    #pragma unroll
    for (int a = 0; a < 2; ++a)
        #pragma unroll
        for (int b = 0; b < 8; ++b) acc[a][b] = (floatx4)0.f;

    for (int c = 0; c < 4; ++c) {
        const unsigned short* srcp =
            ((c < 2) ? featb + (size_t)c * PLANE
                     : hnb + (size_t)(c - 2) * PLANE) + (size_t)base_m * 64;
        #pragma unroll
        for (int it = 0; it < 4; ++it) {          // 1280 slots / 320 threads
            int s = t + it * 320;
            int m = s >> 3, g = s & 7;            // LDS (row m, 16B-granule g)
            const unsigned short* sa = srcp + m * 64 + ((g ^ (m & 7)) << 3);
            __builtin_amdgcn_global_load_lds(
                (const __attribute__((address_space(1))) unsigned int*)sa,
                (__attribute__((address_space(3))) unsigned int*)(As + s * 8),
                16, 0, 0);
        }
        if (t < 256) {
            const unsigned short* bp = Wc + (size_t)c * 128 * 64;
            #pragma unroll
            for (int it = 0; it < 4; ++it) {      // 1024 slots / 256 threads
                int s = t + it * 256;
                int n = s >> 3, g = s & 7;
                const unsigned short* sb = bp + n * 64 + ((g ^ (n & 7)) << 3);
                __builtin_amdgcn_global_load_lds(
                    (const __attribute__((address_space(1))) unsigned int*)sb,
                    (__attribute__((address_space(3))) unsigned int*)(Bs + s * 8),
                    16, 0, 0);
            }
        }
        __syncthreads();

        #pragma unroll
        for (int sstep = 0; sstep < 2; ++sstep) {
            int gk = sstep * 4 + (lane >> 4);     // source 16B-granule wanted
            short8 af[2];
            #pragma unroll
            for (int mt = 0; mt < 2; ++mt) {
                int m = w * 32 + mt * 16 + (lane & 15);
                af[mt] = *reinterpret_cast<const short8*>(
                    As + m * 64 + ((gk ^ (m & 7)) << 3));
            }
            #pragma unroll
            for (int nt = 0; nt < 8; ++nt) {
                int n = nt * 16 + (lane & 15);
                short8 bf = *reinterpret_cast<const short8*>(
                    Bs + n * 64 + ((gk ^ (n & 7)) << 3));
                acc[0][nt] = __builtin_amdgcn_mfma_f32_16x16x32_bf16(
                    af[0], bf, acc[0][nt], 0, 0, 0);
                acc[1][nt] = __builtin_amdgcn_mfma_f32_16x16x32_bf16(
                    af[1], bf, acc[1][nt], 0, 0, 0);
            }
        }
        __syncthreads();
    }

    int colb = lane & 15;
    int quad = lane >> 4;
    #pragma unroll
    for (int nt = 0; nt < 8; ++nt) {
        int col = nt * 16 + colb;
        float bb = bself[col] + bneigh[col];
        #pragma unroll
        for (int mt = 0; mt < 2; ++mt) {
            #pragma unroll
            for (int r = 0; r < 4; ++r) {
                int row = base_m + w * 32 + mt * 16 + quad * 4 + r;
                out[(size_t)row * DIM + col] = acc[mt][nt][r] + bb;
            }
        }
    }
}

// ---------------------------------------------------------------------------
// INSTRUMENTATION LAUNCH: fill x3 (with re-zeros), gather x2 (idempotent).
// delta = dur - 148.3 - ~7us overhead = 2*F + G ; with F+G ~ 39 both resolve.
// ---------------------------------------------------------------------------
extern "C" void kernel_launch(void* const* d_in, const int* in_sizes, int n_in,
                              void* d_out, int out_size, void* d_ws, size_t ws_size,
                              hipStream_t stream)
{
    const float* feat   = (const float*)d_in[0];
    const int*   src    = (const int*)d_in[1];
    const int*   dst    = (const int*)d_in[2];
    const float* Wself  = (const float*)d_in[3];
    const float* bself  = (const float*)d_in[4];
    const float* Wneigh = (const float*)d_in[5];
    const float* bneigh = (const float*)d_in[6];
    float* out = (float*)d_out;

    char* ws = (char*)d_ws;
    unsigned short* featb = (unsigned short*)(ws);
    unsigned short* hnb   = (unsigned short*)(ws + 10240000);
    unsigned short* colf  = (unsigned short*)(ws + 20480000);
    unsigned short* Wc    = (unsigned short*)(ws + 24320000);
    int*            cnt   = (int*)(ws + 24385536);

    k_prep<<<2785, 256, 0, stream>>>(feat, Wself, Wneigh, featb, Wc, cnt);

    k_fill<<<(NE + 255) / 256, 256, 0, stream>>>(src, dst, cnt, colf);
    k_zero<<<157, 256, 0, stream>>>(cnt);
    k_fill<<<(NE + 255) / 256, 256, 0, stream>>>(src, dst, cnt, colf);
    k_zero<<<157, 256, 0, stream>>>(cnt);
    k_fill<<<(NE + 255) / 256, 256, 0, stream>>>(src, dst, cnt, colf);

    k_gather<<<(NN * 64) / 256, 256, 0, stream>>>(
        (const unsigned int*)featb, cnt, colf, (unsigned int*)hnb);
    k_gather<<<(NN * 64) / 256, 256, 0, stream>>>(
        (const unsigned int*)featb, cnt, colf, (unsigned int*)hnb);

    k_gemm<<<NN / 160, 320, 0, stream>>>(featb, hnb, Wc, bself, bneigh, out);
}

// Round 7
// 171.302 us; speedup vs baseline: 1.3460x; 1.3460x over previous
//
#include <hip/hip_runtime.h>
#include <cstddef>

constexpr int NN  = 40000;   // nodes
constexpr int NE  = 640000;  // edges
constexpr int DIM = 128;     // D_IN == D_OUT
constexpr int CAP = 48;      // per-node neighbor capacity (max deg ~36 for Poisson(16))
constexpr int PLANE = NN * 64;   // shorts per 64-dim plane
constexpr int NCH = 256;     // edge chunks (counting-sort)
constexpr int ECH = NE / NCH;    // 2500 edges per chunk

typedef __attribute__((ext_vector_type(8))) short short8;   // 8 bf16 (4 VGPRs)
typedef __attribute__((ext_vector_type(4))) float floatx4;  // MFMA acc

// fp32 -> bf16 with round-to-nearest-even
__device__ __forceinline__ unsigned short f2bf(float x) {
    union { float f; unsigned int i; } v; v.f = x;
    unsigned int u = v.i;
    return (unsigned short)((u + 0x7fffu + ((u >> 16) & 1u)) >> 16);
}
__device__ __forceinline__ float bflo2f(unsigned int u) {   // low bf16 -> f32
    union { unsigned int i; float f; } v; v.i = u << 16; return v.f;
}
__device__ __forceinline__ float bfhi2f(unsigned int u) {   // high bf16 -> f32
    union { unsigned int i; float f; } v; v.i = u & 0xffff0000u; return v.f;
}

// ---------------------------------------------------------------------------
// Prep: [blocks 0..2499] cast feat fp32 -> bf16 planes featb[2][NN][64]
//       [blocks 2500..2627] transpose+cast W to Wc[4][128][64]
//       [blocks 2628..2784] zero cnt[NN] (harmless; k_scan overwrites)
// ---------------------------------------------------------------------------
__global__ __launch_bounds__(256) void k_prep(
    const float* __restrict__ feat, const float* __restrict__ Wself,
    const float* __restrict__ Wneigh, unsigned short* __restrict__ featb,
    unsigned short* __restrict__ Wc, int* __restrict__ cnt)
{
    int b = blockIdx.x, t = threadIdx.x;
    if (b < 2500) {
        int idx8 = b * 256 + t;          // 640000 groups of 8 elements
        int n  = idx8 >> 4;              // 16 groups per row
        int d0 = (idx8 & 15) << 3;       // dim base 0,8,...,120
        const float4* fp =
            reinterpret_cast<const float4*>(feat + (size_t)n * DIM + d0);
        float4 v0 = fp[0], v1 = fp[1];
        unsigned int p0 = (unsigned int)f2bf(v0.x) | ((unsigned int)f2bf(v0.y) << 16);
        unsigned int p1 = (unsigned int)f2bf(v0.z) | ((unsigned int)f2bf(v0.w) << 16);
        unsigned int p2 = (unsigned int)f2bf(v1.x) | ((unsigned int)f2bf(v1.y) << 16);
        unsigned int p3 = (unsigned int)f2bf(v1.z) | ((unsigned int)f2bf(v1.w) << 16);
        int plane = d0 >> 6, off = d0 & 63;
        *reinterpret_cast<uint4*>(
            featb + (size_t)plane * PLANE + (size_t)n * 64 + off) =
            make_uint4(p0, p1, p2, p3);
    } else if (b < 2628) {
        int idx = (b - 2500) * 256 + t;  // 0..32767
        int c = idx >> 13, n = (idx >> 6) & 127, kp = idx & 63;
        int k = c * 64 + kp;
        float w = (k < DIM) ? Wself[(size_t)k * DIM + n]
                            : Wneigh[(size_t)(k - DIM) * DIM + n];
        Wc[idx] = f2bf(w);
    } else {
        int i = (b - 2628) * 256 + t;
        if (i < NN) cnt[i] = 0;
    }
}

// ---------------------------------------------------------------------------
// Counting-sort CSR build — replaces the global-atomic fill (F ~ 35us, the
// measured hotspot: 640k device-scope atomics ~ 18G/s throughput limit).
// K1 k_hist: per-chunk dst histogram via LDS atomics (4 quarter-passes of
//            10k u32 bins), packed u8 -> hist[256][40000].
// ---------------------------------------------------------------------------
__global__ __launch_bounds__(256) void k_hist(
    const int* __restrict__ dst, unsigned char* __restrict__ hist)
{
    __shared__ unsigned short d16[ECH];     // 5000 B
    __shared__ unsigned int   bins[10000];  // 40000 B
    int b = blockIdx.x, t = threadIdx.x;
    const int* dp = dst + b * ECH;
    for (int i = t; i < ECH; i += 256) d16[i] = (unsigned short)dp[i];
    for (int q = 0; q < 4; ++q) {
        int off = q * 10000;
        for (int i = t; i < 10000; i += 256) bins[i] = 0;
        __syncthreads();
        for (int i = t; i < ECH; i += 256) {
            int d = d16[i];
            if (d >= off && d < off + 10000) atomicAdd(&bins[d - off], 1u);
        }
        __syncthreads();
        // pack 4 bins per u32 store (counts <= 36, fit u8)
        for (int i = t; i < 2500; i += 256) {
            unsigned int p = (bins[4*i] & 255u) | ((bins[4*i+1] & 255u) << 8)
                           | ((bins[4*i+2] & 255u) << 16) | ((bins[4*i+3] & 255u) << 24);
            *reinterpret_cast<unsigned int*>(
                hist + (size_t)b * NN + off + 4 * i) = p;
        }
        __syncthreads();
    }
}

// ---------------------------------------------------------------------------
// K2 k_scan: in-place exclusive prefix over chunks per node -> base offsets;
// writes true cnt[n]. 200 blocks x 200 nodes; thread t owns chunk-row t.
// ---------------------------------------------------------------------------
__global__ __launch_bounds__(256) void k_scan(
    unsigned char* __restrict__ hist, int* __restrict__ cnt)
{
    __shared__ unsigned char l[NCH * 200];  // 51200 B
    int n0 = blockIdx.x * 200, t = threadIdx.x;
    unsigned int* lrow = reinterpret_cast<unsigned int*>(l + t * 200);
    const unsigned int* rp =
        reinterpret_cast<const unsigned int*>(hist + (size_t)t * NN + n0);
    #pragma unroll
    for (int i = 0; i < 50; ++i) lrow[i] = rp[i];
    __syncthreads();
    if (t < 200) {
        int run = 0;
        for (int b2 = 0; b2 < NCH; ++b2) {
            int v = l[b2 * 200 + t];
            l[b2 * 200 + t] = (unsigned char)run;
            run += v;
        }
        cnt[n0 + t] = run;
    }
    __syncthreads();
    unsigned int* wp = reinterpret_cast<unsigned int*>(hist + (size_t)t * NN + n0);
    #pragma unroll
    for (int i = 0; i < 50; ++i) wp[i] = lrow[i];
}

// ---------------------------------------------------------------------------
// K3 k_scat: re-read chunk; slot = base[chunk][dst] + LDS-atomic local rank;
// fire-and-forget u16 store into colf. Zero global atomics.
// ---------------------------------------------------------------------------
__global__ __launch_bounds__(256) void k_scat(
    const int* __restrict__ src, const int* __restrict__ dst,
    const unsigned char* __restrict__ base,
    unsigned short* __restrict__ colf)
{
    __shared__ unsigned short d16[ECH];     // 5000 B
    __shared__ unsigned short s16[ECH];     // 5000 B
    __shared__ unsigned int   bins[10000];  // 40000 B
    __shared__ unsigned char  bq[10000];    // 10000 B  (total 60000 B)
    int b = blockIdx.x, t = threadIdx.x;
    const int* dp = dst + b * ECH;
    const int* sp = src + b * ECH;
    for (int i = t; i < ECH; i += 256) {
        d16[i] = (unsigned short)dp[i];
        s16[i] = (unsigned short)sp[i];
    }
    for (int q = 0; q < 4; ++q) {
        int off = q * 10000;
        for (int i = t; i < 10000; i += 256) bins[i] = 0;
        const unsigned int* bp =
            reinterpret_cast<const unsigned int*>(base + (size_t)b * NN + off);
        unsigned int* bq32 = reinterpret_cast<unsigned int*>(bq);
        for (int i = t; i < 2500; i += 256) bq32[i] = bp[i];
        __syncthreads();
        for (int i = t; i < ECH; i += 256) {
            int d = d16[i];
            if (d >= off && d < off + 10000) {
                int lp  = (int)atomicAdd(&bins[d - off], 1u);
                int pos = (int)bq[d - off] + lp;
                if (pos < CAP) colf[d * CAP + pos] = s16[i];
            }
        }
        __syncthreads();
    }
}

// ---------------------------------------------------------------------------
// Gather + mean over bf16 planes (r2/r4 proven form — measured ~free, frozen).
// ---------------------------------------------------------------------------
__global__ __launch_bounds__(256) void k_gather(
    const unsigned int* __restrict__ fb32,   // featb viewed as [2][NN][32] uint
    const int* __restrict__ cnt,
    const unsigned short* __restrict__ colf,
    unsigned int* __restrict__ hnb32)        // hnb viewed as [2][NN][32] uint
{
    int gtid = blockIdx.x * blockDim.x + threadIdx.x;
    int n = gtid >> 6;
    if (n >= NN) return;
    int lane = threadIdx.x & 63;

    int deg = cnt[n];
    int m = min(deg, CAP);
    int sv = (lane < m) ? (int)colf[n * CAP + lane] : 0;

    int vb = (lane >> 5) * (NN * 32) + (lane & 31);   // plane base + lane offset
    float ax0 = 0.f, ay0 = 0.f, ax1 = 0.f, ay1 = 0.f;
    int i = 0;
    for (; i + 7 < m; i += 8) {
        int s0 = __shfl(sv, i),     s1 = __shfl(sv, i + 1);
        int s2 = __shfl(sv, i + 2), s3 = __shfl(sv, i + 3);
        int s4 = __shfl(sv, i + 4), s5 = __shfl(sv, i + 5);
        int s6 = __shfl(sv, i + 6), s7 = __shfl(sv, i + 7);
        unsigned int u0 = fb32[vb + s0 * 32];
        unsigned int u1 = fb32[vb + s1 * 32];
        unsigned int u2 = fb32[vb + s2 * 32];
        unsigned int u3 = fb32[vb + s3 * 32];
        unsigned int u4 = fb32[vb + s4 * 32];
        unsigned int u5 = fb32[vb + s5 * 32];
        unsigned int u6 = fb32[vb + s6 * 32];
        unsigned int u7 = fb32[vb + s7 * 32];
        ax0 += bflo2f(u0); ay0 += bfhi2f(u0);
        ax1 += bflo2f(u1); ay1 += bfhi2f(u1);
        ax0 += bflo2f(u2); ay0 += bfhi2f(u2);
        ax1 += bflo2f(u3); ay1 += bfhi2f(u3);
        ax0 += bflo2f(u4); ay0 += bfhi2f(u4);
        ax1 += bflo2f(u5); ay1 += bfhi2f(u5);
        ax0 += bflo2f(u6); ay0 += bfhi2f(u6);
        ax1 += bflo2f(u7); ay1 += bfhi2f(u7);
    }
    for (; i + 3 < m; i += 4) {
        int s0 = __shfl(sv, i),     s1 = __shfl(sv, i + 1);
        int s2 = __shfl(sv, i + 2), s3 = __shfl(sv, i + 3);
        unsigned int u0 = fb32[vb + s0 * 32];
        unsigned int u1 = fb32[vb + s1 * 32];
        unsigned int u2 = fb32[vb + s2 * 32];
        unsigned int u3 = fb32[vb + s3 * 32];
        ax0 += bflo2f(u0); ay0 += bfhi2f(u0);
        ax1 += bflo2f(u1); ay1 += bfhi2f(u1);
        ax0 += bflo2f(u2); ay0 += bfhi2f(u2);
        ax1 += bflo2f(u3); ay1 += bfhi2f(u3);
    }
    for (; i < m; ++i) {
        int s0 = __shfl(sv, i);
        unsigned int u0 = fb32[vb + s0 * 32];
        ax0 += bflo2f(u0); ay0 += bfhi2f(u0);
    }
    float inv = 1.0f / fmaxf((float)deg, 1.0f);
    float ax = (ax0 + ax1) * inv, ay = (ay0 + ay1) * inv;
    hnb32[vb + n * 32] = (unsigned int)f2bf(ax) | ((unsigned int)f2bf(ay) << 16);
}

// ---------------------------------------------------------------------------
// Fused GEMM (r4 proven form, source-swizzled LDS staging).
// ---------------------------------------------------------------------------
__global__ __launch_bounds__(320) void k_gemm(
    const unsigned short* __restrict__ featb,  // [2][NN][64]
    const unsigned short* __restrict__ hnb,    // [2][NN][64]
    const unsigned short* __restrict__ Wc,     // [4][128][64]
    const float* __restrict__ bself, const float* __restrict__ bneigh,
    float* __restrict__ out)                   // [NN,128] fp32
{
    __shared__ unsigned short As[160 * 64];  // 20480 B
    __shared__ unsigned short Bs[128 * 64];  // 16384 B

    int t = threadIdx.x;
    int w = t >> 6;
    int lane = t & 63;
    int base_m = blockIdx.x * 160;

    floatx4 acc[2][8];
    #pragma unroll
    for (int a = 0; a < 2; ++a)
        #pragma unroll
        for (int b = 0; b < 8; ++b) acc[a][b] = (floatx4)0.f;

    for (int c = 0; c < 4; ++c) {
        const unsigned short* srcp =
            ((c < 2) ? featb + (size_t)c * PLANE
                     : hnb + (size_t)(c - 2) * PLANE) + (size_t)base_m * 64;
        #pragma unroll
        for (int it = 0; it < 4; ++it) {          // 1280 slots / 320 threads
            int s = t + it * 320;
            int m = s >> 3, g = s & 7;            // LDS (row m, 16B-granule g)
            const unsigned short* sa = srcp + m * 64 + ((g ^ (m & 7)) << 3);
            __builtin_amdgcn_global_load_lds(
                (const __attribute__((address_space(1))) unsigned int*)sa,
                (__attribute__((address_space(3))) unsigned int*)(As + s * 8),
                16, 0, 0);
        }
        if (t < 256) {
            const unsigned short* bp = Wc + (size_t)c * 128 * 64;
            #pragma unroll
            for (int it = 0; it < 4; ++it) {      // 1024 slots / 256 threads
                int s = t + it * 256;
                int n = s >> 3, g = s & 7;
                const unsigned short* sb = bp + n * 64 + ((g ^ (n & 7)) << 3);
                __builtin_amdgcn_global_load_lds(
                    (const __attribute__((address_space(1))) unsigned int*)sb,
                    (__attribute__((address_space(3))) unsigned int*)(Bs + s * 8),
                    16, 0, 0);
            }
        }
        __syncthreads();

        #pragma unroll
        for (int sstep = 0; sstep < 2; ++sstep) {
            int gk = sstep * 4 + (lane >> 4);     // source 16B-granule wanted
            short8 af[2];
            #pragma unroll
            for (int mt = 0; mt < 2; ++mt) {
                int m = w * 32 + mt * 16 + (lane & 15);
                af[mt] = *reinterpret_cast<const short8*>(
                    As + m * 64 + ((gk ^ (m & 7)) << 3));
            }
            #pragma unroll
            for (int nt = 0; nt < 8; ++nt) {
                int n = nt * 16 + (lane & 15);
                short8 bf = *reinterpret_cast<const short8*>(
                    Bs + n * 64 + ((gk ^ (n & 7)) << 3));
                acc[0][nt] = __builtin_amdgcn_mfma_f32_16x16x32_bf16(
                    af[0], bf, acc[0][nt], 0, 0, 0);
                acc[1][nt] = __builtin_amdgcn_mfma_f32_16x16x32_bf16(
                    af[1], bf, acc[1][nt], 0, 0, 0);
            }
        }
        __syncthreads();
    }

    int colb = lane & 15;
    int quad = lane >> 4;
    #pragma unroll
    for (int nt = 0; nt < 8; ++nt) {
        int col = nt * 16 + colb;
        float bb = bself[col] + bneigh[col];
        #pragma unroll
        for (int mt = 0; mt < 2; ++mt) {
            #pragma unroll
            for (int r = 0; r < 4; ++r) {
                int row = base_m + w * 32 + mt * 16 + quad * 4 + r;
                out[(size_t)row * DIM + col] = acc[mt][nt][r] + bb;
            }
        }
    }
}

// ---------------------------------------------------------------------------
extern "C" void kernel_launch(void* const* d_in, const int* in_sizes, int n_in,
                              void* d_out, int out_size, void* d_ws, size_t ws_size,
                              hipStream_t stream)
{
    const float* feat   = (const float*)d_in[0];
    const int*   src    = (const int*)d_in[1];
    const int*   dst    = (const int*)d_in[2];
    const float* Wself  = (const float*)d_in[3];
    const float* bself  = (const float*)d_in[4];
    const float* Wneigh = (const float*)d_in[5];
    const float* bneigh = (const float*)d_in[6];
    float* out = (float*)d_out;

    // Workspace layout (bytes):
    //   featb [2][NN][64] bf16 @ 0           (10,240,000)
    //   hnb   [2][NN][64] bf16 @ 10,240,000  (10,240,000)
    //   colf  [NN][CAP]   u16  @ 20,480,000  ( 3,840,000)
    //   Wc    [4][128][64]bf16 @ 24,320,000  (    65,536)
    //   cnt   [NN]        i32  @ 24,385,536  (   160,000)
    //   hist  [256][NN]   u8   @ 24,545,536  (10,240,000)
    // total 34,785,536 B
    char* ws = (char*)d_ws;
    unsigned short* featb = (unsigned short*)(ws);
    unsigned short* hnb   = (unsigned short*)(ws + 10240000);
    unsigned short* colf  = (unsigned short*)(ws + 20480000);
    unsigned short* Wc    = (unsigned short*)(ws + 24320000);
    int*            cnt   = (int*)(ws + 24385536);
    unsigned char*  hist  = (unsigned char*)(ws + 24545536);

    k_prep<<<2785, 256, 0, stream>>>(feat, Wself, Wneigh, featb, Wc, cnt);

    k_hist<<<NCH, 256, 0, stream>>>(dst, hist);
    k_scan<<<NN / 200, 256, 0, stream>>>(hist, cnt);
    k_scat<<<NCH, 256, 0, stream>>>(src, dst, hist, colf);

    k_gather<<<(NN * 64) / 256, 256, 0, stream>>>(
        (const unsigned int*)featb, cnt, colf, (unsigned int*)hnb);

    k_gemm<<<NN / 160, 320, 0, stream>>>(featb, hnb, Wc, bself, bneigh, out);
}